// Round 7
// baseline (345.574 us; speedup 1.0000x reference)
//
#include <hip/hip_runtime.h>
#include <cstdint>

typedef __bf16 bf16_t;
typedef __attribute__((ext_vector_type(8))) __bf16 bf16x8;
typedef __attribute__((ext_vector_type(4))) __bf16 bf16x4;
typedef __attribute__((ext_vector_type(4))) float f32x4;

#define MFMA16(a, b, c) __builtin_amdgcn_mfma_f32_16x16x32_bf16((a), (b), (c), 0, 0, 0)

// async global->LDS DMA, 16B per lane: lane i lands at ldsbase + i*16.
// ldsbase MUST be wave-uniform; global src is per-lane.
#define GLOAD16(g, l) __builtin_amdgcn_global_load_lds(                      \
    (const __attribute__((address_space(1))) void*)(g),                      \
    (__attribute__((address_space(3))) void*)(l), 16, 0, 0)

// fast GELU: tanh form, exp2-domain. max dev from exact erf-GELU ~5e-4.
__device__ inline float gelu_f(float v) {
    const float u = v + 0.044715f * v * v * v;
    return v / (1.0f + exp2f(-2.3022038f * u));
}

// ---------------- fused: fp32->bf16 weight convert (4 arrays) + LayerNorm1 ----------------
// blocks [0,3456): cvt — 864 qkv / 288 proj / 1152 fc1 / 1152 fc2 (2048 elems/block)
// blocks [3456,5504): ln1 — 4 rows/block, wave per row (768 cols), fp32 in -> bf16 out
__global__ __launch_bounds__(256) void cvtln_kernel(const float* __restrict__ s0, bf16_t* __restrict__ d0,
                                                    const float* __restrict__ s1, bf16_t* __restrict__ d1,
                                                    const float* __restrict__ s2, bf16_t* __restrict__ d2,
                                                    const float* __restrict__ s3, bf16_t* __restrict__ d3,
                                                    const float* __restrict__ x,
                                                    const float* __restrict__ gw,
                                                    const float* __restrict__ bw,
                                                    bf16_t* __restrict__ out) {
    const int blk = blockIdx.x;
    if (blk < 3456) {
        const float* s; bf16_t* d; int base;
        if (blk < 864)       { s = s0; d = d0; base = blk; }
        else if (blk < 1152) { s = s1; d = d1; base = blk - 864; }
        else if (blk < 2304) { s = s2; d = d2; base = blk - 1152; }
        else                 { s = s3; d = d3; base = blk - 2304; }
        const int i = (base * 256 + threadIdx.x) * 8;
        const float4* sp = (const float4*)(s + i);
        float4 a = sp[0], b = sp[1];
        bf16x8 o;
        o[0] = (bf16_t)a.x; o[1] = (bf16_t)a.y; o[2] = (bf16_t)a.z; o[3] = (bf16_t)a.w;
        o[4] = (bf16_t)b.x; o[5] = (bf16_t)b.y; o[6] = (bf16_t)b.z; o[7] = (bf16_t)b.w;
        *(bf16x8*)(d + i) = o;
        return;
    }
    const int row  = (blk - 3456) * 4 + (threadIdx.x >> 6);
    const int lane = threadIdx.x & 63;
    const float4* xr = (const float4*)(x + (long)row * 768);
    float4 v[3];
    float s = 0.f, q = 0.f;
#pragma unroll
    for (int j = 0; j < 3; ++j) {
        v[j] = xr[j * 64 + lane];
        s += v[j].x + v[j].y + v[j].z + v[j].w;
        q += v[j].x * v[j].x + v[j].y * v[j].y + v[j].z * v[j].z + v[j].w * v[j].w;
    }
#pragma unroll
    for (int off = 32; off > 0; off >>= 1) {
        s += __shfl_xor(s, off);
        q += __shfl_xor(q, off);
    }
    const float mu = s * (1.0f / 768.0f);
    const float rs = rsqrtf(q * (1.0f / 768.0f) - mu * mu + 1e-5f);
#pragma unroll
    for (int j = 0; j < 3; ++j) {
        float4 g4 = ((const float4*)gw)[j * 64 + lane];
        float4 b4 = ((const float4*)bw)[j * 64 + lane];
        bf16x4 o;
        o[0] = (bf16_t)((v[j].x - mu) * rs * g4.x + b4.x);
        o[1] = (bf16_t)((v[j].y - mu) * rs * g4.y + b4.y);
        o[2] = (bf16_t)((v[j].z - mu) * rs * g4.z + b4.z);
        o[3] = (bf16_t)((v[j].w - mu) * rs * g4.w + b4.w);
        *(bf16x4*)(out + (long)row * 768 + (j * 64 + lane) * 4) = o;
    }
}

// ---------------- LayerNorm: wave per row (768 cols), fp32 in -> bf16 out ----------------
__global__ __launch_bounds__(256) void ln_kernel(const float* __restrict__ x,
                                                 const float* __restrict__ gw,
                                                 const float* __restrict__ bw,
                                                 bf16_t* __restrict__ out) {
    const int row  = blockIdx.x * 4 + (threadIdx.x >> 6);
    const int lane = threadIdx.x & 63;
    const float4* xr = (const float4*)(x + (long)row * 768);
    float4 v[3];
    float s = 0.f, q = 0.f;
#pragma unroll
    for (int j = 0; j < 3; ++j) {
        v[j] = xr[j * 64 + lane];
        s += v[j].x + v[j].y + v[j].z + v[j].w;
        q += v[j].x * v[j].x + v[j].y * v[j].y + v[j].z * v[j].z + v[j].w * v[j].w;
    }
#pragma unroll
    for (int off = 32; off > 0; off >>= 1) {
        s += __shfl_xor(s, off);
        q += __shfl_xor(q, off);
    }
    const float mu = s * (1.0f / 768.0f);
    const float rs = rsqrtf(q * (1.0f / 768.0f) - mu * mu + 1e-5f);
#pragma unroll
    for (int j = 0; j < 3; ++j) {
        float4 g4 = ((const float4*)gw)[j * 64 + lane];
        float4 b4 = ((const float4*)bw)[j * 64 + lane];
        bf16x4 o;
        o[0] = (bf16_t)((v[j].x - mu) * rs * g4.x + b4.x);
        o[1] = (bf16_t)((v[j].y - mu) * rs * g4.y + b4.y);
        o[2] = (bf16_t)((v[j].z - mu) * rs * g4.z + b4.z);
        o[3] = (bf16_t)((v[j].w - mu) * rs * g4.w + b4.w);
        *(bf16x4*)(out + (long)row * 768 + (j * 64 + lane) * 4) = o;
    }
}

// ---------------- GEMM 128x128, XCD-swizzled 1D grid, 3-buffer async pipeline --------------
// Depth-2 global_load_lds pipeline: tiles t and t+1 always in flight (8 loads outstanding).
// Main loop waits vmcnt(4) (tile t landed; t+1 still flying) -> raw barrier -> issue t+2 ->
// compute t. vmcnt never drains to 0 in the main loop (T4). Epilogue slabs alias the dead
// staging LDS, keeping the block at 48KB.
// SWZ=1: LDS chunk-rotation swizzle (T2 via pre-swizzled global source, m173/m201 pattern):
//   slot (row, c) holds A(row, (c - (row>>1)) & 3), c = 16B chunk of a 64B row.
//   Kills the 8-way ds_read bank conflict (R6: 4.9M -> 196K cyc) BUT de-coalesces the
//   staging DMA (rotated per-lane source). Net WIN on qkv/proj/fc2 (latency slack),
//   net LOSS on fc1 (staging-critical: 68 -> 88 µs) — so fc1 runs SWZ=0. [R6 A/B]
// MODE 0: QKV split-scatter: q->outb[bh][n][64], k->o1[bh][n][64],
//         v->o2[bh][64][1024'] transposed + KEY-PERMUTED (c = (tok&15)*8 + ((tok>>4)&7)).
// MODE 2: out_bf16 = gelu(acc + bias)  (fc1), LDS-transpose epilogue -> bf16x8 stores.
// MODE 3: outf_f32 = acc + bias + res  (proj / fc2), fp32 LDS-transpose epilogue.
template <int MODE, int NC, int RPX, int SWZ>
__global__ __launch_bounds__(256) void gemm_bt(const bf16_t* __restrict__ A,
                                               const bf16_t* __restrict__ Bw,
                                               const float* __restrict__ bias,
                                               bf16_t* __restrict__ outb,
                                               bf16_t* __restrict__ o1,
                                               bf16_t* __restrict__ o2,
                                               int Nn, int K,
                                               const float* __restrict__ resf,
                                               float* __restrict__ outf) {
    __shared__ __align__(16) char smem[3 * (128 * 32 + 128 * 32) * 2];  // 48 KB
    bf16_t* As = (bf16_t*)smem;                       // 3 bufs x 4096 elems
    bf16_t* Bs = (bf16_t*)(smem + 3 * 128 * 32 * 2);  // 3 bufs x 4096 elems
    const int id = blockIdx.x;
    const int xcd = id & 7, sblk = id >> 3;
    const int tn = (sblk % NC) * 128;
    const int tm = (xcd * RPX + sblk / NC) * 128;
    const int w = threadIdx.x >> 6, l = threadIdx.x & 63;
    const int quad = l >> 4, r16 = l & 15;
    const int wm = (w >> 1) * 64, wn = (w & 1) * 64;
    f32x4 acc[4][4] = {};
    // stage-side source chunk rotation (SWZ=1) or linear (SWZ=0)
    const int csrc = SWZ ? ((((l & 3) - ((l >> 3) & 3)) & 3) * 8) : ((l & 3) * 8);
    const bf16_t* ga = A  + (long)(tm + w * 32 + (l >> 2)) * K + csrc;
    const bf16_t* gb = Bw + (long)(tn + w * 32 + (l >> 2)) * K + csrc;
    // read-side chunk rotation: row = 16m + r16 -> (row>>1)&3 == (r16>>1)&3
    const int cswz = SWZ ? (((quad + (r16 >> 1)) & 3) * 8) : (quad * 8);
    const int lw = w * 1024;   // wave-uniform LDS base (elements)
    const int NK = K >> 5;

    auto issue = [&](int t) {
        const bf16_t* gan = ga + t * 32;
        const bf16_t* gbn = gb + t * 32;
        bf16_t* ab = As + (t % 3) * 4096;
        bf16_t* bb = Bs + (t % 3) * 4096;
        GLOAD16(gan,          ab + lw);
        GLOAD16(gan + 16 * K, ab + lw + 512);
        GLOAD16(gbn,          bb + lw);
        GLOAD16(gbn + 16 * K, bb + lw + 512);
    };
    auto compute = [&](int t) {
        const bf16_t* ab = As + (t % 3) * 4096;
        const bf16_t* bb = Bs + (t % 3) * 4096;
        bf16x8 af[4], bfr[4];
#pragma unroll
        for (int i = 0; i < 4; ++i) {
            af[i]  = *(const bf16x8*)&ab[(wm + i * 16 + r16) * 32 + cswz];
            bfr[i] = *(const bf16x8*)&bb[(wn + i * 16 + r16) * 32 + cswz];
        }
#pragma unroll
        for (int i = 0; i < 4; ++i)
#pragma unroll
            for (int j = 0; j < 4; ++j)
                acc[i][j] = MFMA16(af[i], bfr[j], acc[i][j]);
    };

    issue(0);
    issue(1);
    for (int t = 0; t < NK - 1; ++t) {
        asm volatile("s_waitcnt vmcnt(4)" ::: "memory");  // tile t landed (t+1 still in flight)
        __builtin_amdgcn_s_barrier();
        if (t + 2 < NK) issue(t + 2);
        compute(t);
    }
    asm volatile("s_waitcnt vmcnt(0)" ::: "memory");
    __builtin_amdgcn_s_barrier();
    compute(NK - 1);

    __syncthreads();                       // staging dead; alias epilogue slabs onto it
    if (MODE == 3) {
        // proj/fc2: fp32 transpose slab (per-wave 16x68 f32, private), residual add, float4 stores
        float* tf = (float*)smem + w * 16 * 68;
#pragma unroll
        for (int i = 0; i < 4; ++i) {
#pragma unroll
            for (int j = 0; j < 4; ++j) {
                const float bv = bias[tn + wn + j * 16 + r16];
#pragma unroll
                for (int rr = 0; rr < 4; ++rr)
                    tf[(quad * 4 + rr) * 68 + j * 16 + r16] = acc[i][j][rr] + bv;
            }
            const int grow = tm + wm + i * 16 + (l >> 2);
#pragma unroll
            for (int it = 0; it < 4; ++it) {
                const int gcol = tn + wn + (l & 3) * 4 + it * 16;
                f32x4 vv = *(const f32x4*)&tf[(l >> 2) * 68 + (l & 3) * 4 + it * 16];
                const float4 rv = *(const float4*)(resf + (long)grow * Nn + gcol);
                float4 ov;
                ov.x = rv.x + vv[0]; ov.y = rv.y + vv[1];
                ov.z = rv.z + vv[2]; ov.w = rv.w + vv[3];
                *(float4*)(outf + (long)grow * Nn + gcol) = ov;
            }
        }
        return;
    }
    bf16_t* tw = (bf16_t*)smem + w * 16 * 72;
    if (MODE == 0) {
        const int sect = (tn + wn) / 768;               // wave-uniform (64-aligned)
        const int cwb  = tn + wn - sect * 768;
        const int h    = cwb >> 6;                      // wave-uniform head
        if (sect == 2) {
            // V: permuted-transposed scatter (scalar b16; this kernel has latency slack)
#pragma unroll
            for (int i = 0; i < 4; ++i) {
                const int r0 = tm + wm + i * 16 + quad * 4;
                const int b = r0 >> 10, n0 = r0 & 1023;
#pragma unroll
                for (int j = 0; j < 4; ++j) {
                    const int d = j * 16 + r16;
                    const float bv = bias[tn + wn + j * 16 + r16];
                    bf16_t* dst = o2 + ((long)(b * 12 + h) * 64 + d) * 1024;
#pragma unroll
                    for (int rr = 0; rr < 4; ++rr) {
                        const int nn = n0 + rr;
                        const int c = ((nn & 15) << 3) | ((nn >> 4) & 7);
                        dst[(nn & 0x380) + c] = (bf16_t)(acc[i][j][rr] + bv);
                    }
                }
            }
        } else {
            bf16_t* dstbuf = (sect == 0 ? outb : o1);
#pragma unroll
            for (int i = 0; i < 4; ++i) {
#pragma unroll
                for (int j = 0; j < 4; ++j) {
                    const float bv = bias[tn + wn + j * 16 + r16];
#pragma unroll
                    for (int rr = 0; rr < 4; ++rr)
                        tw[(quad * 4 + rr) * 72 + j * 16 + r16] = (bf16_t)(acc[i][j][rr] + bv);
                }
                const int tok = tm + wm + i * 16 + (l >> 2);
                const int b = tok >> 10, n0 = tok & 1023;
                const long base = (long)(b * 12 + h) * 65536 + (long)n0 * 64;
#pragma unroll
                for (int it = 0; it < 2; ++it) {
                    bf16x8 vv = *(const bf16x8*)&tw[(l >> 2) * 72 + (l & 3) * 8 + it * 32];
                    *(bf16x8*)(dstbuf + base + (l & 3) * 8 + it * 32) = vv;
                }
            }
        }
    } else {
        // FC1: gelu -> LDS transpose -> bf16x8 row-major stores
#pragma unroll
        for (int i = 0; i < 4; ++i) {
#pragma unroll
            for (int j = 0; j < 4; ++j) {
                const float bv = bias[tn + wn + j * 16 + r16];
#pragma unroll
                for (int rr = 0; rr < 4; ++rr)
                    tw[(quad * 4 + rr) * 72 + j * 16 + r16] = (bf16_t)gelu_f(acc[i][j][rr] + bv);
            }
            const int grow = tm + wm + i * 16 + (l >> 2);
#pragma unroll
            for (int it = 0; it < 2; ++it) {
                bf16x8 vv = *(const bf16x8*)&tw[(l >> 2) * 72 + (l & 3) * 8 + it * 32];
                *(bf16x8*)(outb + (long)grow * Nn + tn + wn + (l & 3) * 8 + it * 32) = vv;
            }
        }
    }
}

// ---------------- Flash attention: K-tile 128 + reg-prefetch + vector P-writes (r9) ----------
// grid (96 bh, 8 qt): XCD = bh%8, per-head K/V L2-resident. block 256 = 4 waves, wave = 32 q-rows.
// Keys within each 128-tile are PERMUTED (c = (k&15)*8 + (k>>4)); vtb is written pre-permuted by
// the QKV epilogue, so P-writes become bf16x8 and PV is consistent. Softmax is permutation-invariant.
// T5: setprio(1) around both MFMA clusters.
__global__ __launch_bounds__(256, 3) void attn_kernel(const bf16_t* __restrict__ qh,
                                                      const bf16_t* __restrict__ kh,
                                                      const bf16_t* __restrict__ vt,
                                                      bf16_t* __restrict__ ctx) {
    __shared__ __align__(16) bf16_t Ks[128 * 72];     // K-tile [key][d], pad 72
    __shared__ __align__(16) bf16_t Vt[64 * 136];     // V^T-tile [d][c], pad 136 (permuted cols)
    __shared__ __align__(16) bf16_t Ps[4 * 16 * 136]; // per-wave P buffer [16 q][c]
    const int w = threadIdx.x >> 6, l = threadIdx.x & 63;
    const int quad = l >> 4, r16 = l & 15;
    const int bh = blockIdx.x, qt = blockIdx.y;
    const bf16_t* qp = qh + (long)bh * 65536;
    const bf16_t* kp = kh + (long)bh * 65536;
    const bf16_t* vp = vt + (long)bh * 65536;
    const int q0 = qt * 128 + w * 32;
    const float SC = 0.18033688011f;  // (1/8) * log2(e): softmax in exp2 domain

    bf16x8 qf[2][2];
#pragma unroll
    for (int mt = 0; mt < 2; ++mt)
#pragma unroll
        for (int kq = 0; kq < 2; ++kq)
            qf[mt][kq] = *(const bf16x8*)(qp + (long)(q0 + mt * 16 + r16) * 64 + kq * 32 + quad * 8);

    float lsum[2][4] = {};   // per-lane partial row sums (16 lanes of a quad share rows)
    f32x4 oacc[2][4] = {};
    bf16_t* pw = Ps + w * 16 * 136;

    // register prefetch of K/V staging (tile kt+1 loaded during tile kt compute)
    bf16x8 kpre[4], vpre[4];
#pragma unroll
    for (int c = 0; c < 4; ++c) {
        const int cc = threadIdx.x + c * 256;
        kpre[c] = *(const bf16x8*)(kp + (long)(cc >> 3) * 64 + (cc & 7) * 8);
        vpre[c] = *(const bf16x8*)(vp + (long)(cc >> 4) * 1024 + (cc & 15) * 8);
    }

    for (int kt = 0; kt < 8; ++kt) {
        __syncthreads();    // all waves done reading LDS of tile kt-1
#pragma unroll
        for (int c = 0; c < 4; ++c) {
            const int cc = threadIdx.x + c * 256;
            *(bf16x8*)&Ks[(cc >> 3) * 72 + (cc & 7) * 8] = kpre[c];
            *(bf16x8*)&Vt[(cc >> 4) * 136 + (cc & 15) * 8] = vpre[c];
        }
        __syncthreads();
        if (kt < 7) {
            const int kb = (kt + 1) * 128;
#pragma unroll
            for (int c = 0; c < 4; ++c) {
                const int cc = threadIdx.x + c * 256;
                kpre[c] = *(const bf16x8*)(kp + (long)(kb + (cc >> 3)) * 64 + (cc & 7) * 8);
                vpre[c] = *(const bf16x8*)(vp + (long)(cc >> 4) * 1024 + kb + (cc & 15) * 8);
            }
        }

#pragma unroll
        for (int mt = 0; mt < 2; ++mt) {
            f32x4 s[8] = {};
            __builtin_amdgcn_s_setprio(1);
#pragma unroll
            for (int nt = 0; nt < 8; ++nt) {
                bf16x8 kf0 = *(const bf16x8*)&Ks[(nt * 16 + r16) * 72 + quad * 8];
                bf16x8 kf1 = *(const bf16x8*)&Ks[(nt * 16 + r16) * 72 + 32 + quad * 8];
                s[nt] = MFMA16(qf[mt][0], kf0, s[nt]);
                s[nt] = MFMA16(qf[mt][1], kf1, s[nt]);
            }
            __builtin_amdgcn_s_setprio(0);
            // p = exp2(s*SC); P-write VECTORIZED: row q = quad*4+rr, col c = r16*8+nt
#pragma unroll
            for (int rr = 0; rr < 4; ++rr) {
                bf16x8 pv;
#pragma unroll
                for (int nt = 0; nt < 8; ++nt) {
                    const float p = exp2f(s[nt][rr] * SC);
                    lsum[mt][rr] += p;
                    pv[nt] = (bf16_t)p;
                }
                *(bf16x8*)&pw[(quad * 4 + rr) * 136 + r16 * 8] = pv;
            }
            // O += P V  (both operands in permuted-c order; sum over c == sum over keys)
            __builtin_amdgcn_s_setprio(1);
#pragma unroll
            for (int kc = 0; kc < 4; ++kc) {
                bf16x8 pf = *(const bf16x8*)&pw[r16 * 136 + kc * 32 + quad * 8];
#pragma unroll
                for (int dt = 0; dt < 4; ++dt) {
                    bf16x8 vf = *(const bf16x8*)&Vt[(dt * 16 + r16) * 136 + kc * 32 + quad * 8];
                    oacc[mt][dt] = MFMA16(pf, vf, oacc[mt][dt]);
                }
            }
            __builtin_amdgcn_s_setprio(0);
        }
        // no trailing barrier: loop-top barrier protects LDS reuse
    }
#pragma unroll
    for (int mt = 0; mt < 2; ++mt)
#pragma unroll
        for (int rr = 0; rr < 4; ++rr) {
#pragma unroll
            for (int off = 1; off < 16; off <<= 1)
                lsum[mt][rr] += __shfl_xor(lsum[mt][rr], off);
        }
    // epilogue: O/l -> per-wave LDS slab [16 tok][72] (reuse Ps) -> bf16x8 stores.
    const int b = bh / 12, h = bh % 12;
    const long tb = (long)b * 1024;
#pragma unroll
    for (int mt = 0; mt < 2; ++mt) {
#pragma unroll
        for (int dt = 0; dt < 4; ++dt)
#pragma unroll
            for (int rr = 0; rr < 4; ++rr)
                pw[(quad * 4 + rr) * 72 + dt * 16 + r16] =
                    (bf16_t)(oacc[mt][dt][rr] / lsum[mt][rr]);
        const int tok = q0 + mt * 16 + (l >> 2);
        const int off = (l & 3) * 16;
        bf16_t* dst = ctx + (tb + tok) * 768 + h * 64 + off;
        const bf16_t* src = &pw[(l >> 2) * 72 + off];
#pragma unroll
        for (int it = 0; it < 2; ++it)
            *(bf16x8*)(dst + it * 8) = *(const bf16x8*)(src + it * 8);
    }
}

// ---------------- launch ----------------
extern "C" void kernel_launch(void* const* d_in, const int* in_sizes, int n_in,
                              void* d_out, int out_size, void* d_ws, size_t ws_size,
                              hipStream_t stream) {
    const float* x      = (const float*)d_in[0];
    const float* ln1_g  = (const float*)d_in[1];
    const float* ln1_b  = (const float*)d_in[2];
    const float* qkv_w  = (const float*)d_in[3];
    const float* qkv_b  = (const float*)d_in[4];
    const float* proj_w = (const float*)d_in[5];
    const float* proj_b = (const float*)d_in[6];
    const float* ln2_g  = (const float*)d_in[7];
    const float* ln2_b  = (const float*)d_in[8];
    const float* fc1_w  = (const float*)d_in[9];
    const float* fc1_b  = (const float*)d_in[10];
    const float* fc2_w  = (const float*)d_in[11];
    const float* fc2_b  = (const float*)d_in[12];

    char* p = (char*)d_ws;
    bf16_t* wqkv  = (bf16_t*)p; p += (size_t)2304 * 768 * 2;
    bf16_t* wproj = (bf16_t*)p; p += (size_t)768 * 768 * 2;
    bf16_t* wfc1  = (bf16_t*)p; p += (size_t)3072 * 768 * 2;
    bf16_t* wfc2  = (bf16_t*)p; p += (size_t)768 * 3072 * 2;
    bf16_t* h1    = (bf16_t*)p; p += (size_t)8192 * 768 * 2;
    bf16_t* qhb   = (bf16_t*)p; p += (size_t)96 * 1024 * 64 * 2;
    bf16_t* khb   = (bf16_t*)p; p += (size_t)96 * 1024 * 64 * 2;
    bf16_t* vtb   = (bf16_t*)p; p += (size_t)96 * 64 * 1024 * 2;
    bf16_t* ctx   = (bf16_t*)p; p += (size_t)8192 * 768 * 2;
    float*  x2    = (float*)p;  p += (size_t)8192 * 768 * 4;
    bf16_t* h2    = (bf16_t*)p; p += (size_t)8192 * 768 * 2;
    bf16_t* a1    = (bf16_t*)p; p += (size_t)8192 * 3072 * 2;

    cvtln_kernel<<<5504, 256, 0, stream>>>(qkv_w, wqkv, proj_w, wproj, fc1_w, wfc1, fc2_w, wfc2,
                                           x, ln1_g, ln1_b, h1);
    gemm_bt<0, 18, 8, 1><<<1152, 256, 0, stream>>>(h1, wqkv, qkv_b, qhb, khb, vtb, 2304, 768,
                                                   nullptr, nullptr);
    attn_kernel<<<dim3(96, 8), 256, 0, stream>>>(qhb, khb, vtb, ctx);
    gemm_bt<3, 6, 8, 1><<<384, 256, 0, stream>>>(ctx, wproj, proj_b, nullptr, nullptr, nullptr,
                                                 768, 768, x, x2);
    ln_kernel<<<2048, 256, 0, stream>>>(x2, ln2_g, ln2_b, h2);
    gemm_bt<2, 24, 8, 0><<<1536, 256, 0, stream>>>(h2, wfc1, fc1_b, a1, nullptr, nullptr, 3072, 768,
                                                   nullptr, nullptr);
    gemm_bt<3, 6, 8, 1><<<384, 256, 0, stream>>>(a1, wfc2, fc2_b, nullptr, nullptr, nullptr,
                                                 768, 3072, x2, (float*)d_out);
}

// Round 8
// 343.479 us; speedup vs baseline: 1.0061x; 1.0061x over previous
//
#include <hip/hip_runtime.h>
#include <cstdint>

typedef __bf16 bf16_t;
typedef __attribute__((ext_vector_type(8))) __bf16 bf16x8;
typedef __attribute__((ext_vector_type(4))) __bf16 bf16x4;
typedef __attribute__((ext_vector_type(4))) float f32x4;

#define MFMA16(a, b, c) __builtin_amdgcn_mfma_f32_16x16x32_bf16((a), (b), (c), 0, 0, 0)

// async global->LDS DMA, 16B per lane: lane i lands at ldsbase + i*16.
// ldsbase MUST be wave-uniform; global src is per-lane.
#define GLOAD16(g, l) __builtin_amdgcn_global_load_lds(                      \
    (const __attribute__((address_space(1))) void*)(g),                      \
    (__attribute__((address_space(3))) void*)(l), 16, 0, 0)

// fast GELU: tanh form, exp2-domain. max dev from exact erf-GELU ~5e-4.
__device__ inline float gelu_f(float v) {
    const float u = v + 0.044715f * v * v * v;
    return v / (1.0f + exp2f(-2.3022038f * u));
}

// ---------------- fused: fp32->bf16 weight convert (4 arrays) + LayerNorm1 ----------------
// blocks [0,3456): cvt — 864 qkv / 288 proj / 1152 fc1 / 1152 fc2 (2048 elems/block)
// blocks [3456,5504): ln1 — 4 rows/block, wave per row (768 cols), fp32 in -> bf16 out
__global__ __launch_bounds__(256) void cvtln_kernel(const float* __restrict__ s0, bf16_t* __restrict__ d0,
                                                    const float* __restrict__ s1, bf16_t* __restrict__ d1,
                                                    const float* __restrict__ s2, bf16_t* __restrict__ d2,
                                                    const float* __restrict__ s3, bf16_t* __restrict__ d3,
                                                    const float* __restrict__ x,
                                                    const float* __restrict__ gw,
                                                    const float* __restrict__ bw,
                                                    bf16_t* __restrict__ out) {
    const int blk = blockIdx.x;
    if (blk < 3456) {
        const float* s; bf16_t* d; int base;
        if (blk < 864)       { s = s0; d = d0; base = blk; }
        else if (blk < 1152) { s = s1; d = d1; base = blk - 864; }
        else if (blk < 2304) { s = s2; d = d2; base = blk - 1152; }
        else                 { s = s3; d = d3; base = blk - 2304; }
        const int i = (base * 256 + threadIdx.x) * 8;
        const float4* sp = (const float4*)(s + i);
        float4 a = sp[0], b = sp[1];
        bf16x8 o;
        o[0] = (bf16_t)a.x; o[1] = (bf16_t)a.y; o[2] = (bf16_t)a.z; o[3] = (bf16_t)a.w;
        o[4] = (bf16_t)b.x; o[5] = (bf16_t)b.y; o[6] = (bf16_t)b.z; o[7] = (bf16_t)b.w;
        *(bf16x8*)(d + i) = o;
        return;
    }
    const int row  = (blk - 3456) * 4 + (threadIdx.x >> 6);
    const int lane = threadIdx.x & 63;
    const float4* xr = (const float4*)(x + (long)row * 768);
    float4 v[3];
    float s = 0.f, q = 0.f;
#pragma unroll
    for (int j = 0; j < 3; ++j) {
        v[j] = xr[j * 64 + lane];
        s += v[j].x + v[j].y + v[j].z + v[j].w;
        q += v[j].x * v[j].x + v[j].y * v[j].y + v[j].z * v[j].z + v[j].w * v[j].w;
    }
#pragma unroll
    for (int off = 32; off > 0; off >>= 1) {
        s += __shfl_xor(s, off);
        q += __shfl_xor(q, off);
    }
    const float mu = s * (1.0f / 768.0f);
    const float rs = rsqrtf(q * (1.0f / 768.0f) - mu * mu + 1e-5f);
#pragma unroll
    for (int j = 0; j < 3; ++j) {
        float4 g4 = ((const float4*)gw)[j * 64 + lane];
        float4 b4 = ((const float4*)bw)[j * 64 + lane];
        bf16x4 o;
        o[0] = (bf16_t)((v[j].x - mu) * rs * g4.x + b4.x);
        o[1] = (bf16_t)((v[j].y - mu) * rs * g4.y + b4.y);
        o[2] = (bf16_t)((v[j].z - mu) * rs * g4.z + b4.z);
        o[3] = (bf16_t)((v[j].w - mu) * rs * g4.w + b4.w);
        *(bf16x4*)(out + (long)row * 768 + (j * 64 + lane) * 4) = o;
    }
}

// ---------------- LayerNorm: wave per row (768 cols), fp32 in -> bf16 out ----------------
__global__ __launch_bounds__(256) void ln_kernel(const float* __restrict__ x,
                                                 const float* __restrict__ gw,
                                                 const float* __restrict__ bw,
                                                 bf16_t* __restrict__ out) {
    const int row  = blockIdx.x * 4 + (threadIdx.x >> 6);
    const int lane = threadIdx.x & 63;
    const float4* xr = (const float4*)(x + (long)row * 768);
    float4 v[3];
    float s = 0.f, q = 0.f;
#pragma unroll
    for (int j = 0; j < 3; ++j) {
        v[j] = xr[j * 64 + lane];
        s += v[j].x + v[j].y + v[j].z + v[j].w;
        q += v[j].x * v[j].x + v[j].y * v[j].y + v[j].z * v[j].z + v[j].w * v[j].w;
    }
#pragma unroll
    for (int off = 32; off > 0; off >>= 1) {
        s += __shfl_xor(s, off);
        q += __shfl_xor(q, off);
    }
    const float mu = s * (1.0f / 768.0f);
    const float rs = rsqrtf(q * (1.0f / 768.0f) - mu * mu + 1e-5f);
#pragma unroll
    for (int j = 0; j < 3; ++j) {
        float4 g4 = ((const float4*)gw)[j * 64 + lane];
        float4 b4 = ((const float4*)bw)[j * 64 + lane];
        bf16x4 o;
        o[0] = (bf16_t)((v[j].x - mu) * rs * g4.x + b4.x);
        o[1] = (bf16_t)((v[j].y - mu) * rs * g4.y + b4.y);
        o[2] = (bf16_t)((v[j].z - mu) * rs * g4.z + b4.z);
        o[3] = (bf16_t)((v[j].w - mu) * rs * g4.w + b4.w);
        *(bf16x4*)(out + (long)row * 768 + (j * 64 + lane) * 4) = o;
    }
}

// ---------------- GEMM 128x128, XCD-swizzled 1D grid, 3-buffer async pipeline --------------
// Depth-2 global_load_lds pipeline: tiles t and t+1 always in flight (8 loads outstanding).
// Main loop waits vmcnt(4) (tile t landed; t+1 still flying) -> raw barrier -> issue t+2 ->
// compute t. vmcnt never drains to 0 in the main loop (T4). Epilogue slabs alias the dead
// staging LDS, keeping the block at 48KB.
// LDS chunk-rotation swizzle (T2 via pre-swizzled global source, m173/m201 pattern):
//   slot (row, c) holds A(row, (c - (row>>1)) & 3), where c indexes 16B chunks of a 64B row.
//   Stage: lane l (dest row l>>2, chunk l&3) sources global chunk ((l&3) - (l>>3)) & 3.
//   Read: A(row, quad) lives at chunk (quad + (row>>1)) & 3.
//   Effect: ds_read_b128 bank spread 8-way -> 2-way (R6: conflicts 4.9M -> 196K cyc).
//   [R6/R7 A/B note: this config measured the session-best total (342.1); the split-swizzle
//    variant (fc1 linear) measured 345.6 despite fc1 itself being 19µs faster.]
// MODE 0: QKV split-scatter: q->outb[bh][n][64], k->o1[bh][n][64],
//         v->o2[bh][64][1024'] transposed + KEY-PERMUTED (c = (tok&15)*8 + ((tok>>4)&7)).
// MODE 2: out_bf16 = gelu(acc + bias)  (fc1), LDS-transpose epilogue -> bf16x8 stores.
// MODE 3: outf_f32 = acc + bias + res  (proj / fc2), fp32 LDS-transpose epilogue.
template <int MODE, int NC, int RPX>
__global__ __launch_bounds__(256) void gemm_bt(const bf16_t* __restrict__ A,
                                               const bf16_t* __restrict__ Bw,
                                               const float* __restrict__ bias,
                                               bf16_t* __restrict__ outb,
                                               bf16_t* __restrict__ o1,
                                               bf16_t* __restrict__ o2,
                                               int Nn, int K,
                                               const float* __restrict__ resf,
                                               float* __restrict__ outf) {
    __shared__ __align__(16) char smem[3 * (128 * 32 + 128 * 32) * 2];  // 48 KB
    bf16_t* As = (bf16_t*)smem;                       // 3 bufs x 4096 elems
    bf16_t* Bs = (bf16_t*)(smem + 3 * 128 * 32 * 2);  // 3 bufs x 4096 elems
    const int id = blockIdx.x;
    const int xcd = id & 7, sblk = id >> 3;
    const int tn = (sblk % NC) * 128;
    const int tm = (xcd * RPX + sblk / NC) * 128;
    const int w = threadIdx.x >> 6, l = threadIdx.x & 63;
    const int quad = l >> 4, r16 = l & 15;
    const int wm = (w >> 1) * 64, wn = (w & 1) * 64;
    f32x4 acc[4][4] = {};
    // stage-side source chunk rotation (see header comment)
    const int csrc = (((l & 3) - ((l >> 3) & 3)) & 3) * 8;
    const bf16_t* ga = A  + (long)(tm + w * 32 + (l >> 2)) * K + csrc;
    const bf16_t* gb = Bw + (long)(tn + w * 32 + (l >> 2)) * K + csrc;
    // read-side chunk rotation: row = 16m + r16 -> (row>>1)&3 == (r16>>1)&3
    const int cswz = ((quad + (r16 >> 1)) & 3) * 8;
    const int lw = w * 1024;   // wave-uniform LDS base (elements)
    const int NK = K >> 5;

    auto issue = [&](int t) {
        const bf16_t* gan = ga + t * 32;
        const bf16_t* gbn = gb + t * 32;
        bf16_t* ab = As + (t % 3) * 4096;
        bf16_t* bb = Bs + (t % 3) * 4096;
        GLOAD16(gan,          ab + lw);
        GLOAD16(gan + 16 * K, ab + lw + 512);
        GLOAD16(gbn,          bb + lw);
        GLOAD16(gbn + 16 * K, bb + lw + 512);
    };
    auto compute = [&](int t) {
        const bf16_t* ab = As + (t % 3) * 4096;
        const bf16_t* bb = Bs + (t % 3) * 4096;
        bf16x8 af[4], bfr[4];
#pragma unroll
        for (int i = 0; i < 4; ++i) {
            af[i]  = *(const bf16x8*)&ab[(wm + i * 16 + r16) * 32 + cswz];
            bfr[i] = *(const bf16x8*)&bb[(wn + i * 16 + r16) * 32 + cswz];
        }
#pragma unroll
        for (int i = 0; i < 4; ++i)
#pragma unroll
            for (int j = 0; j < 4; ++j)
                acc[i][j] = MFMA16(af[i], bfr[j], acc[i][j]);
    };

    issue(0);
    issue(1);
    for (int t = 0; t < NK - 1; ++t) {
        asm volatile("s_waitcnt vmcnt(4)" ::: "memory");  // tile t landed (t+1 still in flight)
        __builtin_amdgcn_s_barrier();
        if (t + 2 < NK) issue(t + 2);
        compute(t);
    }
    asm volatile("s_waitcnt vmcnt(0)" ::: "memory");
    __builtin_amdgcn_s_barrier();
    compute(NK - 1);

    __syncthreads();                       // staging dead; alias epilogue slabs onto it
    if (MODE == 3) {
        // proj/fc2: fp32 transpose slab (per-wave 16x68 f32, private), residual add, float4 stores
        float* tf = (float*)smem + w * 16 * 68;
#pragma unroll
        for (int i = 0; i < 4; ++i) {
#pragma unroll
            for (int j = 0; j < 4; ++j) {
                const float bv = bias[tn + wn + j * 16 + r16];
#pragma unroll
                for (int rr = 0; rr < 4; ++rr)
                    tf[(quad * 4 + rr) * 68 + j * 16 + r16] = acc[i][j][rr] + bv;
            }
            const int grow = tm + wm + i * 16 + (l >> 2);
#pragma unroll
            for (int it = 0; it < 4; ++it) {
                const int gcol = tn + wn + (l & 3) * 4 + it * 16;
                f32x4 vv = *(const f32x4*)&tf[(l >> 2) * 68 + (l & 3) * 4 + it * 16];
                const float4 rv = *(const float4*)(resf + (long)grow * Nn + gcol);
                float4 ov;
                ov.x = rv.x + vv[0]; ov.y = rv.y + vv[1];
                ov.z = rv.z + vv[2]; ov.w = rv.w + vv[3];
                *(float4*)(outf + (long)grow * Nn + gcol) = ov;
            }
        }
        return;
    }
    bf16_t* tw = (bf16_t*)smem + w * 16 * 72;
    if (MODE == 0) {
        const int sect = (tn + wn) / 768;               // wave-uniform (64-aligned)
        const int cwb  = tn + wn - sect * 768;
        const int h    = cwb >> 6;                      // wave-uniform head
        if (sect == 2) {
            // V: permuted-transposed scatter (scalar b16; this kernel has latency slack)
#pragma unroll
            for (int i = 0; i < 4; ++i) {
                const int r0 = tm + wm + i * 16 + quad * 4;
                const int b = r0 >> 10, n0 = r0 & 1023;
#pragma unroll
                for (int j = 0; j < 4; ++j) {
                    const int d = j * 16 + r16;
                    const float bv = bias[tn + wn + j * 16 + r16];
                    bf16_t* dst = o2 + ((long)(b * 12 + h) * 64 + d) * 1024;
#pragma unroll
                    for (int rr = 0; rr < 4; ++rr) {
                        const int nn = n0 + rr;
                        const int c = ((nn & 15) << 3) | ((nn >> 4) & 7);
                        dst[(nn & 0x380) + c] = (bf16_t)(acc[i][j][rr] + bv);
                    }
                }
            }
        } else {
            bf16_t* dstbuf = (sect == 0 ? outb : o1);
#pragma unroll
            for (int i = 0; i < 4; ++i) {
#pragma unroll
                for (int j = 0; j < 4; ++j) {
                    const float bv = bias[tn + wn + j * 16 + r16];
#pragma unroll
                    for (int rr = 0; rr < 4; ++rr)
                        tw[(quad * 4 + rr) * 72 + j * 16 + r16] = (bf16_t)(acc[i][j][rr] + bv);
                }
                const int tok = tm + wm + i * 16 + (l >> 2);
                const int b = tok >> 10, n0 = tok & 1023;
                const long base = (long)(b * 12 + h) * 65536 + (long)n0 * 64;
#pragma unroll
                for (int it = 0; it < 2; ++it) {
                    bf16x8 vv = *(const bf16x8*)&tw[(l >> 2) * 72 + (l & 3) * 8 + it * 32];
                    *(bf16x8*)(dstbuf + base + (l & 3) * 8 + it * 32) = vv;
                }
            }
        }
    } else {
        // FC1: gelu -> LDS transpose -> bf16x8 row-major stores
#pragma unroll
        for (int i = 0; i < 4; ++i) {
#pragma unroll
            for (int j = 0; j < 4; ++j) {
                const float bv = bias[tn + wn + j * 16 + r16];
#pragma unroll
                for (int rr = 0; rr < 4; ++rr)
                    tw[(quad * 4 + rr) * 72 + j * 16 + r16] = (bf16_t)gelu_f(acc[i][j][rr] + bv);
            }
            const int grow = tm + wm + i * 16 + (l >> 2);
#pragma unroll
            for (int it = 0; it < 2; ++it) {
                bf16x8 vv = *(const bf16x8*)&tw[(l >> 2) * 72 + (l & 3) * 8 + it * 32];
                *(bf16x8*)(outb + (long)grow * Nn + tn + wn + (l & 3) * 8 + it * 32) = vv;
            }
        }
    }
}

// ---------------- Flash attention: K-tile 128 + reg-prefetch + vector P-writes (r9) ----------
// grid (96 bh, 8 qt): XCD = bh%8, per-head K/V L2-resident. block 256 = 4 waves, wave = 32 q-rows.
// Keys within each 128-tile are PERMUTED (c = (k&15)*8 + (k>>4)); vtb is written pre-permuted by
// the QKV epilogue, so P-writes become bf16x8 and PV is consistent. Softmax is permutation-invariant.
// T5: setprio(1) around both MFMA clusters.
__global__ __launch_bounds__(256, 3) void attn_kernel(const bf16_t* __restrict__ qh,
                                                      const bf16_t* __restrict__ kh,
                                                      const bf16_t* __restrict__ vt,
                                                      bf16_t* __restrict__ ctx) {
    __shared__ __align__(16) bf16_t Ks[128 * 72];     // K-tile [key][d], pad 72
    __shared__ __align__(16) bf16_t Vt[64 * 136];     // V^T-tile [d][c], pad 136 (permuted cols)
    __shared__ __align__(16) bf16_t Ps[4 * 16 * 136]; // per-wave P buffer [16 q][c]
    const int w = threadIdx.x >> 6, l = threadIdx.x & 63;
    const int quad = l >> 4, r16 = l & 15;
    const int bh = blockIdx.x, qt = blockIdx.y;
    const bf16_t* qp = qh + (long)bh * 65536;
    const bf16_t* kp = kh + (long)bh * 65536;
    const bf16_t* vp = vt + (long)bh * 65536;
    const int q0 = qt * 128 + w * 32;
    const float SC = 0.18033688011f;  // (1/8) * log2(e): softmax in exp2 domain

    bf16x8 qf[2][2];
#pragma unroll
    for (int mt = 0; mt < 2; ++mt)
#pragma unroll
        for (int kq = 0; kq < 2; ++kq)
            qf[mt][kq] = *(const bf16x8*)(qp + (long)(q0 + mt * 16 + r16) * 64 + kq * 32 + quad * 8);

    float lsum[2][4] = {};   // per-lane partial row sums (16 lanes of a quad share rows)
    f32x4 oacc[2][4] = {};
    bf16_t* pw = Ps + w * 16 * 136;

    // register prefetch of K/V staging (tile kt+1 loaded during tile kt compute)
    bf16x8 kpre[4], vpre[4];
#pragma unroll
    for (int c = 0; c < 4; ++c) {
        const int cc = threadIdx.x + c * 256;
        kpre[c] = *(const bf16x8*)(kp + (long)(cc >> 3) * 64 + (cc & 7) * 8);
        vpre[c] = *(const bf16x8*)(vp + (long)(cc >> 4) * 1024 + (cc & 15) * 8);
    }

    for (int kt = 0; kt < 8; ++kt) {
        __syncthreads();    // all waves done reading LDS of tile kt-1
#pragma unroll
        for (int c = 0; c < 4; ++c) {
            const int cc = threadIdx.x + c * 256;
            *(bf16x8*)&Ks[(cc >> 3) * 72 + (cc & 7) * 8] = kpre[c];
            *(bf16x8*)&Vt[(cc >> 4) * 136 + (cc & 15) * 8] = vpre[c];
        }
        __syncthreads();
        if (kt < 7) {
            const int kb = (kt + 1) * 128;
#pragma unroll
            for (int c = 0; c < 4; ++c) {
                const int cc = threadIdx.x + c * 256;
                kpre[c] = *(const bf16x8*)(kp + (long)(kb + (cc >> 3)) * 64 + (cc & 7) * 8);
                vpre[c] = *(const bf16x8*)(vp + (long)(cc >> 4) * 1024 + kb + (cc & 15) * 8);
            }
        }

#pragma unroll
        for (int mt = 0; mt < 2; ++mt) {
            f32x4 s[8] = {};
            __builtin_amdgcn_s_setprio(1);
#pragma unroll
            for (int nt = 0; nt < 8; ++nt) {
                bf16x8 kf0 = *(const bf16x8*)&Ks[(nt * 16 + r16) * 72 + quad * 8];
                bf16x8 kf1 = *(const bf16x8*)&Ks[(nt * 16 + r16) * 72 + 32 + quad * 8];
                s[nt] = MFMA16(qf[mt][0], kf0, s[nt]);
                s[nt] = MFMA16(qf[mt][1], kf1, s[nt]);
            }
            __builtin_amdgcn_s_setprio(0);
            // p = exp2(s*SC); P-write VECTORIZED: row q = quad*4+rr, col c = r16*8+nt
#pragma unroll
            for (int rr = 0; rr < 4; ++rr) {
                bf16x8 pv;
#pragma unroll
                for (int nt = 0; nt < 8; ++nt) {
                    const float p = exp2f(s[nt][rr] * SC);
                    lsum[mt][rr] += p;
                    pv[nt] = (bf16_t)p;
                }
                *(bf16x8*)&pw[(quad * 4 + rr) * 136 + r16 * 8] = pv;
            }
            // O += P V  (both operands in permuted-c order; sum over c == sum over keys)
            __builtin_amdgcn_s_setprio(1);
#pragma unroll
            for (int kc = 0; kc < 4; ++kc) {
                bf16x8 pf = *(const bf16x8*)&pw[r16 * 136 + kc * 32 + quad * 8];
#pragma unroll
                for (int dt = 0; dt < 4; ++dt) {
                    bf16x8 vf = *(const bf16x8*)&Vt[(dt * 16 + r16) * 136 + kc * 32 + quad * 8];
                    oacc[mt][dt] = MFMA16(pf, vf, oacc[mt][dt]);
                }
            }
            __builtin_amdgcn_s_setprio(0);
        }
        // no trailing barrier: loop-top barrier protects LDS reuse
    }
#pragma unroll
    for (int mt = 0; mt < 2; ++mt)
#pragma unroll
        for (int rr = 0; rr < 4; ++rr) {
#pragma unroll
            for (int off = 1; off < 16; off <<= 1)
                lsum[mt][rr] += __shfl_xor(lsum[mt][rr], off);
        }
    // epilogue: O/l -> per-wave LDS slab [16 tok][72] (reuse Ps) -> bf16x8 stores.
    const int b = bh / 12, h = bh % 12;
    const long tb = (long)b * 1024;
#pragma unroll
    for (int mt = 0; mt < 2; ++mt) {
#pragma unroll
        for (int dt = 0; dt < 4; ++dt)
#pragma unroll
            for (int rr = 0; rr < 4; ++rr)
                pw[(quad * 4 + rr) * 72 + dt * 16 + r16] =
                    (bf16_t)(oacc[mt][dt][rr] / lsum[mt][rr]);
        const int tok = q0 + mt * 16 + (l >> 2);
        const int off = (l & 3) * 16;
        bf16_t* dst = ctx + (tb + tok) * 768 + h * 64 + off;
        const bf16_t* src = &pw[(l >> 2) * 72 + off];
#pragma unroll
        for (int it = 0; it < 2; ++it)
            *(bf16x8*)(dst + it * 8) = *(const bf16x8*)(src + it * 8);
    }
}

// ---------------- launch ----------------
extern "C" void kernel_launch(void* const* d_in, const int* in_sizes, int n_in,
                              void* d_out, int out_size, void* d_ws, size_t ws_size,
                              hipStream_t stream) {
    const float* x      = (const float*)d_in[0];
    const float* ln1_g  = (const float*)d_in[1];
    const float* ln1_b  = (const float*)d_in[2];
    const float* qkv_w  = (const float*)d_in[3];
    const float* qkv_b  = (const float*)d_in[4];
    const float* proj_w = (const float*)d_in[5];
    const float* proj_b = (const float*)d_in[6];
    const float* ln2_g  = (const float*)d_in[7];
    const float* ln2_b  = (const float*)d_in[8];
    const float* fc1_w  = (const float*)d_in[9];
    const float* fc1_b  = (const float*)d_in[10];
    const float* fc2_w  = (const float*)d_in[11];
    const float* fc2_b  = (const float*)d_in[12];

    char* p = (char*)d_ws;
    bf16_t* wqkv  = (bf16_t*)p; p += (size_t)2304 * 768 * 2;
    bf16_t* wproj = (bf16_t*)p; p += (size_t)768 * 768 * 2;
    bf16_t* wfc1  = (bf16_t*)p; p += (size_t)3072 * 768 * 2;
    bf16_t* wfc2  = (bf16_t*)p; p += (size_t)768 * 3072 * 2;
    bf16_t* h1    = (bf16_t*)p; p += (size_t)8192 * 768 * 2;
    bf16_t* qhb   = (bf16_t*)p; p += (size_t)96 * 1024 * 64 * 2;
    bf16_t* khb   = (bf16_t*)p; p += (size_t)96 * 1024 * 64 * 2;
    bf16_t* vtb   = (bf16_t*)p; p += (size_t)96 * 64 * 1024 * 2;
    bf16_t* ctx   = (bf16_t*)p; p += (size_t)8192 * 768 * 2;
    float*  x2    = (float*)p;  p += (size_t)8192 * 768 * 4;
    bf16_t* h2    = (bf16_t*)p; p += (size_t)8192 * 768 * 2;
    bf16_t* a1    = (bf16_t*)p; p += (size_t)8192 * 3072 * 2;

    cvtln_kernel<<<5504, 256, 0, stream>>>(qkv_w, wqkv, proj_w, wproj, fc1_w, wfc1, fc2_w, wfc2,
                                           x, ln1_g, ln1_b, h1);
    gemm_bt<0, 18, 8><<<1152, 256, 0, stream>>>(h1, wqkv, qkv_b, qhb, khb, vtb, 2304, 768,
                                                nullptr, nullptr);
    attn_kernel<<<dim3(96, 8), 256, 0, stream>>>(qhb, khb, vtb, ctx);
    gemm_bt<3, 6, 8><<<384, 256, 0, stream>>>(ctx, wproj, proj_b, nullptr, nullptr, nullptr,
                                              768, 768, x, x2);
    ln_kernel<<<2048, 256, 0, stream>>>(x2, ln2_g, ln2_b, h2);
    gemm_bt<2, 24, 8><<<1536, 256, 0, stream>>>(h2, wfc1, fc1_b, a1, nullptr, nullptr, 3072, 768,
                                                nullptr, nullptr);
    gemm_bt<3, 6, 8><<<384, 256, 0, stream>>>(a1, wfc2, fc2_b, nullptr, nullptr, nullptr,
                                              768, 3072, x2, (float*)d_out);
}

// Round 10
// 342.002 us; speedup vs baseline: 1.0104x; 1.0043x over previous
//
#include <hip/hip_runtime.h>
#include <cstdint>

typedef __bf16 bf16_t;
typedef __attribute__((ext_vector_type(8))) __bf16 bf16x8;
typedef __attribute__((ext_vector_type(4))) __bf16 bf16x4;
typedef __attribute__((ext_vector_type(4))) float f32x4;

#define MFMA16(a, b, c) __builtin_amdgcn_mfma_f32_16x16x32_bf16((a), (b), (c), 0, 0, 0)

// async global->LDS DMA, 16B per lane: lane i lands at ldsbase + i*16.
// ldsbase MUST be wave-uniform; global src is per-lane.
#define GLOAD16(g, l) __builtin_amdgcn_global_load_lds(                      \
    (const __attribute__((address_space(1))) void*)(g),                      \
    (__attribute__((address_space(3))) void*)(l), 16, 0, 0)

// fast GELU: tanh form, exp2-domain. max dev from exact erf-GELU ~5e-4.
__device__ inline float gelu_f(float v) {
    const float u = v + 0.044715f * v * v * v;
    return v / (1.0f + exp2f(-2.3022038f * u));
}

// ---------------- fused: fp32->bf16 weight convert (4 arrays) + LayerNorm1 ----------------
// blocks [0,3456): cvt — 864 qkv / 288 proj / 1152 fc1 / 1152 fc2 (2048 elems/block)
// blocks [3456,5504): ln1 — 4 rows/block, wave per row (768 cols), fp32 in -> bf16 out
__global__ __launch_bounds__(256) void cvtln_kernel(const float* __restrict__ s0, bf16_t* __restrict__ d0,
                                                    const float* __restrict__ s1, bf16_t* __restrict__ d1,
                                                    const float* __restrict__ s2, bf16_t* __restrict__ d2,
                                                    const float* __restrict__ s3, bf16_t* __restrict__ d3,
                                                    const float* __restrict__ x,
                                                    const float* __restrict__ gw,
                                                    const float* __restrict__ bw,
                                                    bf16_t* __restrict__ out) {
    const int blk = blockIdx.x;
    if (blk < 3456) {
        const float* s; bf16_t* d; int base;
        if (blk < 864)       { s = s0; d = d0; base = blk; }
        else if (blk < 1152) { s = s1; d = d1; base = blk - 864; }
        else if (blk < 2304) { s = s2; d = d2; base = blk - 1152; }
        else                 { s = s3; d = d3; base = blk - 2304; }
        const int i = (base * 256 + threadIdx.x) * 8;
        const float4* sp = (const float4*)(s + i);
        float4 a = sp[0], b = sp[1];
        bf16x8 o;
        o[0] = (bf16_t)a.x; o[1] = (bf16_t)a.y; o[2] = (bf16_t)a.z; o[3] = (bf16_t)a.w;
        o[4] = (bf16_t)b.x; o[5] = (bf16_t)b.y; o[6] = (bf16_t)b.z; o[7] = (bf16_t)b.w;
        *(bf16x8*)(d + i) = o;
        return;
    }
    const int row  = (blk - 3456) * 4 + (threadIdx.x >> 6);
    const int lane = threadIdx.x & 63;
    const float4* xr = (const float4*)(x + (long)row * 768);
    float4 v[3];
    float s = 0.f, q = 0.f;
#pragma unroll
    for (int j = 0; j < 3; ++j) {
        v[j] = xr[j * 64 + lane];
        s += v[j].x + v[j].y + v[j].z + v[j].w;
        q += v[j].x * v[j].x + v[j].y * v[j].y + v[j].z * v[j].z + v[j].w * v[j].w;
    }
#pragma unroll
    for (int off = 32; off > 0; off >>= 1) {
        s += __shfl_xor(s, off);
        q += __shfl_xor(q, off);
    }
    const float mu = s * (1.0f / 768.0f);
    const float rs = rsqrtf(q * (1.0f / 768.0f) - mu * mu + 1e-5f);
#pragma unroll
    for (int j = 0; j < 3; ++j) {
        float4 g4 = ((const float4*)gw)[j * 64 + lane];
        float4 b4 = ((const float4*)bw)[j * 64 + lane];
        bf16x4 o;
        o[0] = (bf16_t)((v[j].x - mu) * rs * g4.x + b4.x);
        o[1] = (bf16_t)((v[j].y - mu) * rs * g4.y + b4.y);
        o[2] = (bf16_t)((v[j].z - mu) * rs * g4.z + b4.z);
        o[3] = (bf16_t)((v[j].w - mu) * rs * g4.w + b4.w);
        *(bf16x4*)(out + (long)row * 768 + (j * 64 + lane) * 4) = o;
    }
}

// ---------------- LayerNorm: wave per row (768 cols), fp32 in -> bf16 out ----------------
__global__ __launch_bounds__(256) void ln_kernel(const float* __restrict__ x,
                                                 const float* __restrict__ gw,
                                                 const float* __restrict__ bw,
                                                 bf16_t* __restrict__ out) {
    const int row  = blockIdx.x * 4 + (threadIdx.x >> 6);
    const int lane = threadIdx.x & 63;
    const float4* xr = (const float4*)(x + (long)row * 768);
    float4 v[3];
    float s = 0.f, q = 0.f;
#pragma unroll
    for (int j = 0; j < 3; ++j) {
        v[j] = xr[j * 64 + lane];
        s += v[j].x + v[j].y + v[j].z + v[j].w;
        q += v[j].x * v[j].x + v[j].y * v[j].y + v[j].z * v[j].z + v[j].w * v[j].w;
    }
#pragma unroll
    for (int off = 32; off > 0; off >>= 1) {
        s += __shfl_xor(s, off);
        q += __shfl_xor(q, off);
    }
    const float mu = s * (1.0f / 768.0f);
    const float rs = rsqrtf(q * (1.0f / 768.0f) - mu * mu + 1e-5f);
#pragma unroll
    for (int j = 0; j < 3; ++j) {
        float4 g4 = ((const float4*)gw)[j * 64 + lane];
        float4 b4 = ((const float4*)bw)[j * 64 + lane];
        bf16x4 o;
        o[0] = (bf16_t)((v[j].x - mu) * rs * g4.x + b4.x);
        o[1] = (bf16_t)((v[j].y - mu) * rs * g4.y + b4.y);
        o[2] = (bf16_t)((v[j].z - mu) * rs * g4.z + b4.z);
        o[3] = (bf16_t)((v[j].w - mu) * rs * g4.w + b4.w);
        *(bf16x4*)(out + (long)row * 768 + (j * 64 + lane) * 4) = o;
    }
}

// ---------------- GEMM 128x128, XCD-swizzled 1D grid, 3-buffer async pipeline --------------
// Depth-2 global_load_lds pipeline: tiles t and t+1 always in flight (8 loads outstanding).
// Main loop waits vmcnt(4) (tile t landed; t+1 still flying) -> raw barrier -> issue t+2 ->
// compute t. vmcnt never drains to 0 in the main loop (T4). Epilogue slabs alias the dead
// staging LDS, keeping the block at 48KB.
// LDS chunk-rotation swizzle (T2 via pre-swizzled global source, m173/m201 pattern):
//   slot (row, c) holds A(row, (c - (row>>1)) & 3), where c indexes 16B chunks of a 64B row.
//   Stage: lane l (dest row l>>2, chunk l&3) sources global chunk ((l&3) - (l>>3)) & 3.
//   Read: A(row, quad) lives at chunk (quad + (row>>1)) & 3.
//   Effect: ds_read_b128 bank spread 8-way -> 2-way (R6: conflicts 4.9M -> 196K cyc).
//   Used for qkv/proj/fc2 (helps, R5->R6 total A/B); fc1 uses the standalone linear kernel
//   below (swizzle is an 18µs per-kernel LOSS there — staging-critical; R3/R5/R7 vs R6/R8).
// MODE 0: QKV split-scatter: q->outb[bh][n][64], k->o1[bh][n][64],
//         v->o2[bh][64][1024'] transposed + KEY-PERMUTED (c = (tok&15)*8 + ((tok>>4)&7)).
// MODE 3: outf_f32 = acc + bias + res  (proj / fc2), fp32 LDS-transpose epilogue.
template <int MODE, int NC, int RPX>
__global__ __launch_bounds__(256) void gemm_bt(const bf16_t* __restrict__ A,
                                               const bf16_t* __restrict__ Bw,
                                               const float* __restrict__ bias,
                                               bf16_t* __restrict__ outb,
                                               bf16_t* __restrict__ o1,
                                               bf16_t* __restrict__ o2,
                                               int Nn, int K,
                                               const float* __restrict__ resf,
                                               float* __restrict__ outf) {
    __shared__ __align__(16) char smem[3 * (128 * 32 + 128 * 32) * 2];  // 48 KB
    bf16_t* As = (bf16_t*)smem;                       // 3 bufs x 4096 elems
    bf16_t* Bs = (bf16_t*)(smem + 3 * 128 * 32 * 2);  // 3 bufs x 4096 elems
    const int id = blockIdx.x;
    const int xcd = id & 7, sblk = id >> 3;
    const int tn = (sblk % NC) * 128;
    const int tm = (xcd * RPX + sblk / NC) * 128;
    const int w = threadIdx.x >> 6, l = threadIdx.x & 63;
    const int quad = l >> 4, r16 = l & 15;
    const int wm = (w >> 1) * 64, wn = (w & 1) * 64;
    f32x4 acc[4][4] = {};
    // stage-side source chunk rotation (see header comment)
    const int csrc = (((l & 3) - ((l >> 3) & 3)) & 3) * 8;
    const bf16_t* ga = A  + (long)(tm + w * 32 + (l >> 2)) * K + csrc;
    const bf16_t* gb = Bw + (long)(tn + w * 32 + (l >> 2)) * K + csrc;
    // read-side chunk rotation: row = 16m + r16 -> (row>>1)&3 == (r16>>1)&3
    const int cswz = ((quad + (r16 >> 1)) & 3) * 8;
    const int lw = w * 1024;   // wave-uniform LDS base (elements)
    const int NK = K >> 5;

    auto issue = [&](int t) {
        const bf16_t* gan = ga + t * 32;
        const bf16_t* gbn = gb + t * 32;
        bf16_t* ab = As + (t % 3) * 4096;
        bf16_t* bb = Bs + (t % 3) * 4096;
        GLOAD16(gan,          ab + lw);
        GLOAD16(gan + 16 * K, ab + lw + 512);
        GLOAD16(gbn,          bb + lw);
        GLOAD16(gbn + 16 * K, bb + lw + 512);
    };
    auto compute = [&](int t) {
        const bf16_t* ab = As + (t % 3) * 4096;
        const bf16_t* bb = Bs + (t % 3) * 4096;
        bf16x8 af[4], bfr[4];
#pragma unroll
        for (int i = 0; i < 4; ++i) {
            af[i]  = *(const bf16x8*)&ab[(wm + i * 16 + r16) * 32 + cswz];
            bfr[i] = *(const bf16x8*)&bb[(wn + i * 16 + r16) * 32 + cswz];
        }
#pragma unroll
        for (int i = 0; i < 4; ++i)
#pragma unroll
            for (int j = 0; j < 4; ++j)
                acc[i][j] = MFMA16(af[i], bfr[j], acc[i][j]);
    };

    issue(0);
    issue(1);
    for (int t = 0; t < NK - 1; ++t) {
        asm volatile("s_waitcnt vmcnt(4)" ::: "memory");  // tile t landed (t+1 still in flight)
        __builtin_amdgcn_s_barrier();
        if (t + 2 < NK) issue(t + 2);
        compute(t);
    }
    asm volatile("s_waitcnt vmcnt(0)" ::: "memory");
    __builtin_amdgcn_s_barrier();
    compute(NK - 1);

    __syncthreads();                       // staging dead; alias epilogue slabs onto it
    if (MODE == 3) {
        // proj/fc2: fp32 transpose slab (per-wave 16x68 f32, private), residual add, float4 stores
        float* tf = (float*)smem + w * 16 * 68;
#pragma unroll
        for (int i = 0; i < 4; ++i) {
#pragma unroll
            for (int j = 0; j < 4; ++j) {
                const float bv = bias[tn + wn + j * 16 + r16];
#pragma unroll
                for (int rr = 0; rr < 4; ++rr)
                    tf[(quad * 4 + rr) * 68 + j * 16 + r16] = acc[i][j][rr] + bv;
            }
            const int grow = tm + wm + i * 16 + (l >> 2);
#pragma unroll
            for (int it = 0; it < 4; ++it) {
                const int gcol = tn + wn + (l & 3) * 4 + it * 16;
                f32x4 vv = *(const f32x4*)&tf[(l >> 2) * 68 + (l & 3) * 4 + it * 16];
                const float4 rv = *(const float4*)(resf + (long)grow * Nn + gcol);
                float4 ov;
                ov.x = rv.x + vv[0]; ov.y = rv.y + vv[1];
                ov.z = rv.z + vv[2]; ov.w = rv.w + vv[3];
                *(float4*)(outf + (long)grow * Nn + gcol) = ov;
            }
        }
        return;
    }
    bf16_t* tw = (bf16_t*)smem + w * 16 * 72;
    {
        const int sect = (tn + wn) / 768;               // wave-uniform (64-aligned)
        const int cwb  = tn + wn - sect * 768;
        const int h    = cwb >> 6;                      // wave-uniform head
        if (sect == 2) {
            // V: permuted-transposed scatter (scalar b16; this kernel has latency slack)
#pragma unroll
            for (int i = 0; i < 4; ++i) {
                const int r0 = tm + wm + i * 16 + quad * 4;
                const int b = r0 >> 10, n0 = r0 & 1023;
#pragma unroll
                for (int j = 0; j < 4; ++j) {
                    const int d = j * 16 + r16;
                    const float bv = bias[tn + wn + j * 16 + r16];
                    bf16_t* dst = o2 + ((long)(b * 12 + h) * 64 + d) * 1024;
#pragma unroll
                    for (int rr = 0; rr < 4; ++rr) {
                        const int nn = n0 + rr;
                        const int c = ((nn & 15) << 3) | ((nn >> 4) & 7);
                        dst[(nn & 0x380) + c] = (bf16_t)(acc[i][j][rr] + bv);
                    }
                }
            }
        } else {
            bf16_t* dstbuf = (sect == 0 ? outb : o1);
#pragma unroll
            for (int i = 0; i < 4; ++i) {
#pragma unroll
                for (int j = 0; j < 4; ++j) {
                    const float bv = bias[tn + wn + j * 16 + r16];
#pragma unroll
                    for (int rr = 0; rr < 4; ++rr)
                        tw[(quad * 4 + rr) * 72 + j * 16 + r16] = (bf16_t)(acc[i][j][rr] + bv);
                }
                const int tok = tm + wm + i * 16 + (l >> 2);
                const int b = tok >> 10, n0 = tok & 1023;
                const long base = (long)(b * 12 + h) * 65536 + (long)n0 * 64;
#pragma unroll
                for (int it = 0; it < 2; ++it) {
                    bf16x8 vv = *(const bf16x8*)&tw[(l >> 2) * 72 + (l & 3) * 8 + it * 32];
                    *(bf16x8*)(dstbuf + base + (l & 3) * 8 + it * 32) = vv;
                }
            }
        }
    }
}

// ---------------- GEMM 128x128 fc1 (gelu epilogue), LINEAR staging — standalone kernel ------
// Identical pipeline to gemm_bt but with linear (non-swizzled) staging: fc1 is the most
// staging-traffic-intensive dispatch and the swizzle's de-coalesced DMA costs it 18µs
// (69 -> 87µs, R3/R5/R7 vs R6/R8 per-dispatch A/B). Standalone (non-template) so the
// swizzled gemm_bt instantiations' codegen is not perturbed (rule #19 — R7's shared
// template param shifted VGPR 68->76 across the family).
__global__ __launch_bounds__(256) void gemm_fc1(const bf16_t* __restrict__ A,
                                                const bf16_t* __restrict__ Bw,
                                                const float* __restrict__ bias,
                                                bf16_t* __restrict__ outb) {
    constexpr int NC = 24, RPX = 8, Nn = 3072, K = 768, NK = K >> 5;
    __shared__ __align__(16) char smem[3 * (128 * 32 + 128 * 32) * 2];  // 48 KB
    bf16_t* As = (bf16_t*)smem;
    bf16_t* Bs = (bf16_t*)(smem + 3 * 128 * 32 * 2);
    const int id = blockIdx.x;
    const int xcd = id & 7, sblk = id >> 3;
    const int tn = (sblk % NC) * 128;
    const int tm = (xcd * RPX + sblk / NC) * 128;
    const int w = threadIdx.x >> 6, l = threadIdx.x & 63;
    const int quad = l >> 4, r16 = l & 15;
    const int wm = (w >> 1) * 64, wn = (w & 1) * 64;
    f32x4 acc[4][4] = {};
    const bf16_t* ga = A  + (long)(tm + w * 32 + (l >> 2)) * K + (l & 3) * 8;
    const bf16_t* gb = Bw + (long)(tn + w * 32 + (l >> 2)) * K + (l & 3) * 8;
    const int lw = w * 1024;

    auto issue = [&](int t) {
        const bf16_t* gan = ga + t * 32;
        const bf16_t* gbn = gb + t * 32;
        bf16_t* ab = As + (t % 3) * 4096;
        bf16_t* bb = Bs + (t % 3) * 4096;
        GLOAD16(gan,          ab + lw);
        GLOAD16(gan + 16 * K, ab + lw + 512);
        GLOAD16(gbn,          bb + lw);
        GLOAD16(gbn + 16 * K, bb + lw + 512);
    };
    auto compute = [&](int t) {
        const bf16_t* ab = As + (t % 3) * 4096;
        const bf16_t* bb = Bs + (t % 3) * 4096;
        bf16x8 af[4], bfr[4];
#pragma unroll
        for (int i = 0; i < 4; ++i) {
            af[i]  = *(const bf16x8*)&ab[(wm + i * 16 + r16) * 32 + quad * 8];
            bfr[i] = *(const bf16x8*)&bb[(wn + i * 16 + r16) * 32 + quad * 8];
        }
#pragma unroll
        for (int i = 0; i < 4; ++i)
#pragma unroll
            for (int j = 0; j < 4; ++j)
                acc[i][j] = MFMA16(af[i], bfr[j], acc[i][j]);
    };

    issue(0);
    issue(1);
    for (int t = 0; t < NK - 1; ++t) {
        asm volatile("s_waitcnt vmcnt(4)" ::: "memory");
        __builtin_amdgcn_s_barrier();
        if (t + 2 < NK) issue(t + 2);
        compute(t);
    }
    asm volatile("s_waitcnt vmcnt(0)" ::: "memory");
    __builtin_amdgcn_s_barrier();
    compute(NK - 1);

    __syncthreads();                       // staging dead; alias transpose slab
    bf16_t* tw = (bf16_t*)smem + w * 16 * 72;
#pragma unroll
    for (int i = 0; i < 4; ++i) {
#pragma unroll
        for (int j = 0; j < 4; ++j) {
            const float bv = bias[tn + wn + j * 16 + r16];
#pragma unroll
            for (int rr = 0; rr < 4; ++rr)
                tw[(quad * 4 + rr) * 72 + j * 16 + r16] = (bf16_t)gelu_f(acc[i][j][rr] + bv);
        }
        const int grow = tm + wm + i * 16 + (l >> 2);
#pragma unroll
        for (int it = 0; it < 2; ++it) {
            bf16x8 vv = *(const bf16x8*)&tw[(l >> 2) * 72 + (l & 3) * 8 + it * 32];
            *(bf16x8*)(outb + (long)grow * Nn + tn + wn + (l & 3) * 8 + it * 32) = vv;
        }
    }
}

// ---------------- Flash attention: K-tile 128 + reg-prefetch + vector P-writes (r9) ----------
// grid (96 bh, 8 qt): XCD = bh%8, per-head K/V L2-resident. block 256 = 4 waves, wave = 32 q-rows.
// Keys within each 128-tile are PERMUTED (c = (k&15)*8 + (k>>4)); vtb is written pre-permuted by
// the QKV epilogue, so P-writes become bf16x8 and PV is consistent. Softmax is permutation-invariant.
// T5: setprio(1) around both MFMA clusters.
__global__ __launch_bounds__(256, 3) void attn_kernel(const bf16_t* __restrict__ qh,
                                                      const bf16_t* __restrict__ kh,
                                                      const bf16_t* __restrict__ vt,
                                                      bf16_t* __restrict__ ctx) {
    __shared__ __align__(16) bf16_t Ks[128 * 72];     // K-tile [key][d], pad 72
    __shared__ __align__(16) bf16_t Vt[64 * 136];     // V^T-tile [d][c], pad 136 (permuted cols)
    __shared__ __align__(16) bf16_t Ps[4 * 16 * 136]; // per-wave P buffer [16 q][c]
    const int w = threadIdx.x >> 6, l = threadIdx.x & 63;
    const int quad = l >> 4, r16 = l & 15;
    const int bh = blockIdx.x, qt = blockIdx.y;
    const bf16_t* qp = qh + (long)bh * 65536;
    const bf16_t* kp = kh + (long)bh * 65536;
    const bf16_t* vp = vt + (long)bh * 65536;
    const int q0 = qt * 128 + w * 32;
    const float SC = 0.18033688011f;  // (1/8) * log2(e): softmax in exp2 domain

    bf16x8 qf[2][2];
#pragma unroll
    for (int mt = 0; mt < 2; ++mt)
#pragma unroll
        for (int kq = 0; kq < 2; ++kq)
            qf[mt][kq] = *(const bf16x8*)(qp + (long)(q0 + mt * 16 + r16) * 64 + kq * 32 + quad * 8);

    float lsum[2][4] = {};   // per-lane partial row sums (16 lanes of a quad share rows)
    f32x4 oacc[2][4] = {};
    bf16_t* pw = Ps + w * 16 * 136;

    // register prefetch of K/V staging (tile kt+1 loaded during tile kt compute)
    bf16x8 kpre[4], vpre[4];
#pragma unroll
    for (int c = 0; c < 4; ++c) {
        const int cc = threadIdx.x + c * 256;
        kpre[c] = *(const bf16x8*)(kp + (long)(cc >> 3) * 64 + (cc & 7) * 8);
        vpre[c] = *(const bf16x8*)(vp + (long)(cc >> 4) * 1024 + (cc & 15) * 8);
    }

    for (int kt = 0; kt < 8; ++kt) {
        __syncthreads();    // all waves done reading LDS of tile kt-1
#pragma unroll
        for (int c = 0; c < 4; ++c) {
            const int cc = threadIdx.x + c * 256;
            *(bf16x8*)&Ks[(cc >> 3) * 72 + (cc & 7) * 8] = kpre[c];
            *(bf16x8*)&Vt[(cc >> 4) * 136 + (cc & 15) * 8] = vpre[c];
        }
        __syncthreads();
        if (kt < 7) {
            const int kb = (kt + 1) * 128;
#pragma unroll
            for (int c = 0; c < 4; ++c) {
                const int cc = threadIdx.x + c * 256;
                kpre[c] = *(const bf16x8*)(kp + (long)(kb + (cc >> 3)) * 64 + (cc & 7) * 8);
                vpre[c] = *(const bf16x8*)(vp + (long)(cc >> 4) * 1024 + kb + (cc & 15) * 8);
            }
        }

#pragma unroll
        for (int mt = 0; mt < 2; ++mt) {
            f32x4 s[8] = {};
            __builtin_amdgcn_s_setprio(1);
#pragma unroll
            for (int nt = 0; nt < 8; ++nt) {
                bf16x8 kf0 = *(const bf16x8*)&Ks[(nt * 16 + r16) * 72 + quad * 8];
                bf16x8 kf1 = *(const bf16x8*)&Ks[(nt * 16 + r16) * 72 + 32 + quad * 8];
                s[nt] = MFMA16(qf[mt][0], kf0, s[nt]);
                s[nt] = MFMA16(qf[mt][1], kf1, s[nt]);
            }
            __builtin_amdgcn_s_setprio(0);
            // p = exp2(s*SC); P-write VECTORIZED: row q = quad*4+rr, col c = r16*8+nt
#pragma unroll
            for (int rr = 0; rr < 4; ++rr) {
                bf16x8 pv;
#pragma unroll
                for (int nt = 0; nt < 8; ++nt) {
                    const float p = exp2f(s[nt][rr] * SC);
                    lsum[mt][rr] += p;
                    pv[nt] = (bf16_t)p;
                }
                *(bf16x8*)&pw[(quad * 4 + rr) * 136 + r16 * 8] = pv;
            }
            // O += P V  (both operands in permuted-c order; sum over c == sum over keys)
            __builtin_amdgcn_s_setprio(1);
#pragma unroll
            for (int kc = 0; kc < 4; ++kc) {
                bf16x8 pf = *(const bf16x8*)&pw[r16 * 136 + kc * 32 + quad * 8];
#pragma unroll
                for (int dt = 0; dt < 4; ++dt) {
                    bf16x8 vf = *(const bf16x8*)&Vt[(dt * 16 + r16) * 136 + kc * 32 + quad * 8];
                    oacc[mt][dt] = MFMA16(pf, vf, oacc[mt][dt]);
                }
            }
            __builtin_amdgcn_s_setprio(0);
        }
        // no trailing barrier: loop-top barrier protects LDS reuse
    }
#pragma unroll
    for (int mt = 0; mt < 2; ++mt)
#pragma unroll
        for (int rr = 0; rr < 4; ++rr) {
#pragma unroll
            for (int off = 1; off < 16; off <<= 1)
                lsum[mt][rr] += __shfl_xor(lsum[mt][rr], off);
        }
    // epilogue: O/l -> per-wave LDS slab [16 tok][72] (reuse Ps) -> bf16x8 stores.
    const int b = bh / 12, h = bh % 12;
    const long tb = (long)b * 1024;
#pragma unroll
    for (int mt = 0; mt < 2; ++mt) {
#pragma unroll
        for (int dt = 0; dt < 4; ++dt)
#pragma unroll
            for (int rr = 0; rr < 4; ++rr)
                pw[(quad * 4 + rr) * 72 + dt * 16 + r16] =
                    (bf16_t)(oacc[mt][dt][rr] / lsum[mt][rr]);
        const int tok = q0 + mt * 16 + (l >> 2);
        const int off = (l & 3) * 16;
        bf16_t* dst = ctx + (tb + tok) * 768 + h * 64 + off;
        const bf16_t* src = &pw[(l >> 2) * 72 + off];
#pragma unroll
        for (int it = 0; it < 2; ++it)
            *(bf16x8*)(dst + it * 8) = *(const bf16x8*)(src + it * 8);
    }
}

// ---------------- launch ----------------
extern "C" void kernel_launch(void* const* d_in, const int* in_sizes, int n_in,
                              void* d_out, int out_size, void* d_ws, size_t ws_size,
                              hipStream_t stream) {
    const float* x      = (const float*)d_in[0];
    const float* ln1_g  = (const float*)d_in[1];
    const float* ln1_b  = (const float*)d_in[2];
    const float* qkv_w  = (const float*)d_in[3];
    const float* qkv_b  = (const float*)d_in[4];
    const float* proj_w = (const float*)d_in[5];
    const float* proj_b = (const float*)d_in[6];
    const float* ln2_g  = (const float*)d_in[7];
    const float* ln2_b  = (const float*)d_in[8];
    const float* fc1_w  = (const float*)d_in[9];
    const float* fc1_b  = (const float*)d_in[10];
    const float* fc2_w  = (const float*)d_in[11];
    const float* fc2_b  = (const float*)d_in[12];

    char* p = (char*)d_ws;
    bf16_t* wqkv  = (bf16_t*)p; p += (size_t)2304 * 768 * 2;
    bf16_t* wproj = (bf16_t*)p; p += (size_t)768 * 768 * 2;
    bf16_t* wfc1  = (bf16_t*)p; p += (size_t)3072 * 768 * 2;
    bf16_t* wfc2  = (bf16_t*)p; p += (size_t)768 * 3072 * 2;
    bf16_t* h1    = (bf16_t*)p; p += (size_t)8192 * 768 * 2;
    bf16_t* qhb   = (bf16_t*)p; p += (size_t)96 * 1024 * 64 * 2;
    bf16_t* khb   = (bf16_t*)p; p += (size_t)96 * 1024 * 64 * 2;
    bf16_t* vtb   = (bf16_t*)p; p += (size_t)96 * 64 * 1024 * 2;
    bf16_t* ctx   = (bf16_t*)p; p += (size_t)8192 * 768 * 2;
    float*  x2    = (float*)p;  p += (size_t)8192 * 768 * 4;
    bf16_t* h2    = (bf16_t*)p; p += (size_t)8192 * 768 * 2;
    bf16_t* a1    = (bf16_t*)p; p += (size_t)8192 * 3072 * 2;

    cvtln_kernel<<<5504, 256, 0, stream>>>(qkv_w, wqkv, proj_w, wproj, fc1_w, wfc1, fc2_w, wfc2,
                                           x, ln1_g, ln1_b, h1);
    gemm_bt<0, 18, 8><<<1152, 256, 0, stream>>>(h1, wqkv, qkv_b, qhb, khb, vtb, 2304, 768,
                                                nullptr, nullptr);
    attn_kernel<<<dim3(96, 8), 256, 0, stream>>>(qhb, khb, vtb, ctx);
    gemm_bt<3, 6, 8><<<384, 256, 0, stream>>>(ctx, wproj, proj_b, nullptr, nullptr, nullptr,
                                              768, 768, x, x2);
    ln_kernel<<<2048, 256, 0, stream>>>(x2, ln2_g, ln2_b, h2);
    gemm_fc1<<<1536, 256, 0, stream>>>(h2, wfc1, fc1_b, a1);
    gemm_bt<3, 6, 8><<<384, 256, 0, stream>>>(a1, wfc2, fc2_b, nullptr, nullptr, nullptr,
                                              768, 3072, x2, (float*)d_out);
}